// Round 1
// baseline (231.070 us; speedup 1.0000x reference)
//
#include <hip/hip_runtime.h>
#include <hip/hip_bf16.h>
#include <cstdint>

// ---------- types ----------
typedef __bf16 bf8 __attribute__((ext_vector_type(8)));
typedef __bf16 bf4 __attribute__((ext_vector_type(4)));
typedef float  f4  __attribute__((ext_vector_type(4)));

typedef const void __attribute__((address_space(1)))* as1_cvp;
typedef void       __attribute__((address_space(3)))* as3_vp;

#define NEG_INF_F 1000000000000.0f

__device__ __forceinline__ void lds_load16(const __bf16* g, __bf16* l) {
    // async global->LDS, 16B per lane; LDS dst = wave-uniform base + lane*16
    __builtin_amdgcn_global_load_lds((as1_cvp)g, (as3_vp)l, 16, 0, 0);
}

// ---------- shared MFMA GEMM core ----------
// C(128x128) += A(128xK) * Bt(128xK)^T   (both operands k-contiguous, bf16)
// block = 256 threads = 4 waves (2x2 of 64x64), BK=32, 16x16x32 bf16 MFMA.
__device__ __forceinline__ void gemm_tile_core(
    const __bf16* __restrict__ Atile, const __bf16* __restrict__ Btile,
    int lda, int ldb, int Ktot,
    __bf16* sA, __bf16* sB, f4 acc[4][4])
{
    const int t    = threadIdx.x;
    const int wave = t >> 6;
    const int lane = t & 63;
    const int quad = lane >> 4;
    const int m16  = lane & 15;
    const int wm   = (wave >> 1) * 64;
    const int wn   = (wave & 1) * 64;

    for (int k0 = 0; k0 < Ktot; k0 += 32) {
        __syncthreads();   // previous compute done before LDS overwrite
#pragma unroll
        for (int i = 0; i < 2; ++i) {
            const int f   = i * 256 + t;      // 16B chunk id, 0..511
            const int row = f >> 2;           // 4 chunks per 32-elem row
            const int ch  = (f & 3) * 8;      // elem offset in row
            lds_load16(Atile + (size_t)row * lda + k0 + ch,
                       sA + (i * 256 + wave * 64) * 8);
            lds_load16(Btile + (size_t)row * ldb + k0 + ch,
                       sB + (i * 256 + wave * 64) * 8);
        }
        __syncthreads();   // drains vmcnt -> LDS visible

        bf8 af[4], bfr[4];
#pragma unroll
        for (int mi = 0; mi < 4; ++mi)
            af[mi] = *(const bf8*)(sA + (wm + mi * 16 + m16) * 32 + quad * 8);
#pragma unroll
        for (int ni = 0; ni < 4; ++ni)
            bfr[ni] = *(const bf8*)(sB + (wn + ni * 16 + m16) * 32 + quad * 8);
#pragma unroll
        for (int mi = 0; mi < 4; ++mi)
#pragma unroll
            for (int ni = 0; ni < 4; ++ni)
                acc[mi][ni] = __builtin_amdgcn_mfma_f32_16x16x32_bf16(
                    af[mi], bfr[ni], acc[mi][ni], 0, 0, 0);
    }
}

// ---------- kernel 1: cast A fp32 -> bf16 ----------
__global__ __launch_bounds__(256) void cast_a_kernel(
    const float* __restrict__ in, __bf16* __restrict__ out, int n4)
{
    int idx = blockIdx.x * 256 + threadIdx.x;
    if (idx < n4) {
        const float4 v = reinterpret_cast<const float4*>(in)[idx];
        bf4 o = { (__bf16)v.x, (__bf16)v.y, (__bf16)v.z, (__bf16)v.w };
        reinterpret_cast<bf4*>(out)[idx] = o;
    }
}

// ---------- kernel 2: W (768x1152) -> Wt bf16 (1152x768) ----------
__global__ __launch_bounds__(256) void transpose_w_kernel(
    const float* __restrict__ W, __bf16* __restrict__ Wt)
{
    __shared__ __bf16 tile[32][33];
    const int n0 = blockIdx.x * 32;
    const int k0 = blockIdx.y * 32;
    const int tx = threadIdx.x & 31;
    const int ty = threadIdx.x >> 5;   // 0..7
#pragma unroll
    for (int r = 0; r < 32; r += 8)
        tile[ty + r][tx] = (__bf16)W[(size_t)(k0 + ty + r) * 1152 + n0 + tx];
    __syncthreads();
#pragma unroll
    for (int r = 0; r < 32; r += 8)
        Wt[(size_t)(n0 + ty + r) * 768 + k0 + tx] = tile[tx][ty + r];
}

// ---------- kernel 3: proj GEMM + bias + RoPE -> q/k bf16 (b,e,s,64) ----------
__global__ __launch_bounds__(256) void proj_rope_kernel(
    const __bf16* __restrict__ A,    // 8192 x 768
    const __bf16* __restrict__ Wt,   // 1152 x 768
    const float*  __restrict__ bias, // 1152
    __bf16* __restrict__ qbuf, __bf16* __restrict__ kbuf)
{
    __shared__ __bf16 sA[128 * 32];
    __shared__ __bf16 sB[128 * 32];
    f4 acc[4][4] = {};

    const int rowTile = blockIdx.y * 128;   // over M=8192
    const int colTile = blockIdx.x * 128;   // over N=1152
    gemm_tile_core(A + (size_t)rowTile * 768, Wt + (size_t)colTile * 768,
                   768, 768, 768, sA, sB, acc);

    const int t = threadIdx.x, wave = t >> 6, lane = t & 63;
    const int quad = lane >> 4, m16 = lane & 15;
    const int wm = (wave >> 1) * 64, wn = (wave & 1) * 64;

#pragma unroll
    for (int ni = 0; ni < 4; ++ni) {
        const int gc = colTile + wn + ni * 16 + m16;   // 0..1151
        const float bv = bias[gc];
        const int e  = gc >> 7;          // ent 0..8
        const int d  = gc & 63;          // dim within q/k
        const int qk = (gc >> 6) & 1;    // 0=q, 1=k
        // theta_i = 10000^{-i/32} = 2^{-i*log2(10000)/32}
        const float theta = exp2f((float)(d >> 1) * -0.4152410118609203f);
        const float sgn = (d & 1) ? 1.0f : -1.0f;
        __bf16* dst = qk ? kbuf : qbuf;
#pragma unroll
        for (int mi = 0; mi < 4; ++mi) {
#pragma unroll
            for (int r = 0; r < 4; ++r) {
                const int gm = rowTile + wm + mi * 16 + quad * 4 + r;
                const int bb = gm >> 9;      // batch
                const int s  = gm & 511;     // position
                float v = acc[mi][ni][r] + bv;
                // pair partner (col ^ 1) lives in lane ^ 1 (C-layout col = lane&15)
                float p = __shfl_xor(v, 1);
                float sn, cs;
                __sincosf((float)s * theta, &sn, &cs);
                float o = v * cs + sgn * p * sn;
                dst[(size_t)(((bb * 9 + e) * 512 + s)) * 64 + d] = (__bf16)o;
            }
        }
    }
}

// ---------- kernel 4: logits = Q K^T per (b,e), mask, scale ----------
__global__ __launch_bounds__(256) void logits_kernel(
    const __bf16* __restrict__ qbuf, const __bf16* __restrict__ kbuf,
    const float* __restrict__ amask, float* __restrict__ out)
{
    __shared__ __bf16 sA[128 * 32];
    __shared__ __bf16 sB[128 * 32];
    f4 acc[4][4] = {};

    const int be = blockIdx.y;          // 0..143
    const int b  = be / 9;
    const int rowTile = (blockIdx.x >> 2) * 128;
    const int colTile = (blockIdx.x & 3) * 128;
    const __bf16* Q  = qbuf + (size_t)be * 512 * 64;
    const __bf16* Kt = kbuf + (size_t)be * 512 * 64;
    gemm_tile_core(Q + (size_t)rowTile * 64, Kt + (size_t)colTile * 64,
                   64, 64, 64, sA, sB, acc);

    const int t = threadIdx.x, wave = t >> 6, lane = t & 63;
    const int quad = lane >> 4, m16 = lane & 15;
    const int wm = (wave >> 1) * 64, wn = (wave & 1) * 64;

#pragma unroll
    for (int ni = 0; ni < 4; ++ni) {
        const int n = colTile + wn + ni * 16 + m16;
        const float pad    = amask[b * 512 + n];
        const float padoff = (1.0f - pad) * NEG_INF_F;
#pragma unroll
        for (int mi = 0; mi < 4; ++mi) {
#pragma unroll
            for (int r = 0; r < 4; ++r) {
                const int m = rowTile + wm + mi * 16 + quad * 4 + r;
                float v = acc[mi][ni][r] * pad - padoff;
                if (n < m) v -= NEG_INF_F;   // tril(-1) causal-past mask
                out[((size_t)(be * 512 + m) << 9) + n] = v * 0.125f;
            }
        }
    }
}

// ---------- launch ----------
extern "C" void kernel_launch(void* const* d_in, const int* in_sizes, int n_in,
                              void* d_out, int out_size, void* d_ws, size_t ws_size,
                              hipStream_t stream) {
    const float* lhs   = (const float*)d_in[0];  // 16*512*768
    const float* amask = (const float*)d_in[1];  // 16*512
    const float* W     = (const float*)d_in[2];  // 768*1152
    const float* bias  = (const float*)d_in[3];  // 1152
    float* out = (float*)d_out;

    char* ws = (char*)d_ws;
    __bf16* Abf = (__bf16*)ws;                       // 8192*768*2   = 12,582,912 B
    __bf16* Wt  = (__bf16*)(ws + 12582912);          // 1152*768*2   =  1,769,472 B
    __bf16* qb  = (__bf16*)(ws + 14352384);          // 144*512*64*2 =  9,437,184 B
    __bf16* kb  = (__bf16*)(ws + 23789568);          // 144*512*64*2 =  9,437,184 B

    cast_a_kernel<<<6144, 256, 0, stream>>>(lhs, Abf, 1572864);      // 6291456/4
    transpose_w_kernel<<<dim3(36, 24), 256, 0, stream>>>(W, Wt);
    proj_rope_kernel<<<dim3(9, 64), 256, 0, stream>>>(Abf, Wt, bias, qb, kb);
    logits_kernel<<<dim3(16, 144), 256, 0, stream>>>(qb, kb, amask, out);
}

// Round 2
// 227.318 us; speedup vs baseline: 1.0165x; 1.0165x over previous
//
#include <hip/hip_runtime.h>
#include <hip/hip_bf16.h>
#include <cstdint>

// ---------- types ----------
typedef __bf16 bf8 __attribute__((ext_vector_type(8)));
typedef __bf16 bf4 __attribute__((ext_vector_type(4)));
typedef float  f4  __attribute__((ext_vector_type(4)));

typedef const void __attribute__((address_space(1)))* as1_cvp;
typedef void       __attribute__((address_space(3)))* as3_vp;

#define NEG_INF_F 1000000000000.0f

__device__ __forceinline__ void lds_load16(const __bf16* g, __bf16* l) {
    // async global->LDS, 16B per lane; LDS dst = wave-uniform base + lane*16
    __builtin_amdgcn_global_load_lds((as1_cvp)g, (as3_vp)l, 16, 0, 0);
}

// ---------- shared MFMA GEMM core (used by proj) ----------
// C(128x128) += A(128xK) * Bt(128xK)^T   (both operands k-contiguous, bf16)
// block = 256 threads = 4 waves (2x2 of 64x64), BK=32, 16x16x32 bf16 MFMA.
__device__ __forceinline__ void gemm_tile_core(
    const __bf16* __restrict__ Atile, const __bf16* __restrict__ Btile,
    int lda, int ldb, int Ktot,
    __bf16* sA, __bf16* sB, f4 acc[4][4])
{
    const int t    = threadIdx.x;
    const int wave = t >> 6;
    const int lane = t & 63;
    const int quad = lane >> 4;
    const int m16  = lane & 15;
    const int wm   = (wave >> 1) * 64;
    const int wn   = (wave & 1) * 64;

    for (int k0 = 0; k0 < Ktot; k0 += 32) {
        __syncthreads();   // previous compute done before LDS overwrite
#pragma unroll
        for (int i = 0; i < 2; ++i) {
            const int f   = i * 256 + t;      // 16B chunk id, 0..511
            const int row = f >> 2;           // 4 chunks per 32-elem row
            const int ch  = (f & 3) * 8;      // elem offset in row
            lds_load16(Atile + (size_t)row * lda + k0 + ch,
                       sA + (i * 256 + wave * 64) * 8);
            lds_load16(Btile + (size_t)row * ldb + k0 + ch,
                       sB + (i * 256 + wave * 64) * 8);
        }
        __syncthreads();   // drains vmcnt -> LDS visible

        bf8 af[4], bfr[4];
#pragma unroll
        for (int mi = 0; mi < 4; ++mi)
            af[mi] = *(const bf8*)(sA + (wm + mi * 16 + m16) * 32 + quad * 8);
#pragma unroll
        for (int ni = 0; ni < 4; ++ni)
            bfr[ni] = *(const bf8*)(sB + (wn + ni * 16 + m16) * 32 + quad * 8);
#pragma unroll
        for (int mi = 0; mi < 4; ++mi)
#pragma unroll
            for (int ni = 0; ni < 4; ++ni)
                acc[mi][ni] = __builtin_amdgcn_mfma_f32_16x16x32_bf16(
                    af[mi], bfr[ni], acc[mi][ni], 0, 0, 0);
    }
}

// ---------- kernel 1: cast A fp32 -> bf16 ----------
__global__ __launch_bounds__(256) void cast_a_kernel(
    const float* __restrict__ in, __bf16* __restrict__ out, int n4)
{
    int idx = blockIdx.x * 256 + threadIdx.x;
    if (idx < n4) {
        const float4 v = reinterpret_cast<const float4*>(in)[idx];
        bf4 o = { (__bf16)v.x, (__bf16)v.y, (__bf16)v.z, (__bf16)v.w };
        reinterpret_cast<bf4*>(out)[idx] = o;
    }
}

// ---------- kernel 2: W (768x1152) -> Wt bf16 (1152x768) ----------
__global__ __launch_bounds__(256) void transpose_w_kernel(
    const float* __restrict__ W, __bf16* __restrict__ Wt)
{
    __shared__ __bf16 tile[32][33];
    const int n0 = blockIdx.x * 32;
    const int k0 = blockIdx.y * 32;
    const int tx = threadIdx.x & 31;
    const int ty = threadIdx.x >> 5;   // 0..7
#pragma unroll
    for (int r = 0; r < 32; r += 8)
        tile[ty + r][tx] = (__bf16)W[(size_t)(k0 + ty + r) * 1152 + n0 + tx];
    __syncthreads();
#pragma unroll
    for (int r = 0; r < 32; r += 8)
        Wt[(size_t)(n0 + ty + r) * 768 + k0 + tx] = tile[tx][ty + r];
}

// ---------- kernel 3: proj GEMM + bias + RoPE -> q/k bf16 (b,e,s,64) ----------
__global__ __launch_bounds__(256) void proj_rope_kernel(
    const __bf16* __restrict__ A,    // 8192 x 768
    const __bf16* __restrict__ Wt,   // 1152 x 768
    const float*  __restrict__ bias, // 1152
    __bf16* __restrict__ qbuf, __bf16* __restrict__ kbuf)
{
    __shared__ __bf16 sA[128 * 32];
    __shared__ __bf16 sB[128 * 32];
    f4 acc[4][4] = {};

    const int rowTile = blockIdx.y * 128;   // over M=8192
    const int colTile = blockIdx.x * 128;   // over N=1152
    gemm_tile_core(A + (size_t)rowTile * 768, Wt + (size_t)colTile * 768,
                   768, 768, 768, sA, sB, acc);

    const int t = threadIdx.x, wave = t >> 6, lane = t & 63;
    const int quad = lane >> 4, m16 = lane & 15;
    const int wm = (wave >> 1) * 64, wn = (wave & 1) * 64;

#pragma unroll
    for (int ni = 0; ni < 4; ++ni) {
        const int gc = colTile + wn + ni * 16 + m16;   // 0..1151
        const float bv = bias[gc];
        const int e  = gc >> 7;          // ent 0..8
        const int d  = gc & 63;          // dim within q/k
        const int qk = (gc >> 6) & 1;    // 0=q, 1=k
        // theta_i = 10000^{-i/32} = 2^{-i*log2(10000)/32}
        const float theta = exp2f((float)(d >> 1) * -0.4152410118609203f);
        const float sgn = (d & 1) ? 1.0f : -1.0f;
        __bf16* dst = qk ? kbuf : qbuf;
#pragma unroll
        for (int mi = 0; mi < 4; ++mi) {
#pragma unroll
            for (int r = 0; r < 4; ++r) {
                const int gm = rowTile + wm + mi * 16 + quad * 4 + r;
                const int bb = gm >> 9;      // batch
                const int s  = gm & 511;     // position
                float v = acc[mi][ni][r] + bv;
                // pair partner (col ^ 1) lives in lane ^ 1 (C-layout col = lane&15)
                float p = __shfl_xor(v, 1);
                float sn, cs;
                __sincosf((float)s * theta, &sn, &cs);
                float o = v * cs + sgn * p * sn;
                dst[(size_t)(((bb * 9 + e) * 512 + s)) * 64 + d] = (__bf16)o;
            }
        }
    }
}

// ---------- kernel 4: Q-resident streaming logits ----------
// grid (4, 144): block = (rowTile, be). Q tile (128x64) resident in LDS;
// K streamed in 4 chunks of 128 rows, double-buffered via global_load_lds.
// LDS layout: two 128x32 planes per tile (row stride 32 elems = 64 B).
__global__ __launch_bounds__(256, 3) void logits_kernel(
    const __bf16* __restrict__ qbuf, const __bf16* __restrict__ kbuf,
    const float* __restrict__ amask, float* __restrict__ out)
{
    __shared__ __bf16 sQ[2 * 128 * 32];        // 16 KB
    __shared__ __bf16 sK[2][2 * 128 * 32];     // 2 x 16 KB

    const int t    = threadIdx.x;
    const int wave = t >> 6;
    const int lane = t & 63;
    const int quad = lane >> 4;
    const int m16  = lane & 15;
    const int wm   = (wave >> 1) * 64;
    const int wn   = (wave & 1) * 64;

    const int be = blockIdx.y;          // 0..143
    const int b  = be / 9;
    const int rowTile = blockIdx.x * 128;
    const __bf16* Qg = qbuf + (size_t)be * 512 * 64 + (size_t)rowTile * 64;
    const __bf16* Kg = kbuf + (size_t)be * 512 * 64;

    // ---- stage Q (once) and K chunk 0 ----
    // tile = 128 rows x 64 cols, contiguous in global (lda==64).
    // LDS: plane p (k-half), row r, 16B chunk j:
    //   lds chunk l = p*512 + r*4 + j ; global chunk g = r*8 + p*4 + j
#pragma unroll
    for (int i = 0; i < 4; ++i) {
        const int l = i * 256 + t;
        const int p = l >> 9;
        const int r = (l >> 2) & 127;
        const int j = l & 3;
        const int g = r * 8 + p * 4 + j;
        lds_load16(Qg + g * 8, sQ + (i * 256 + wave * 64) * 8);
        lds_load16(Kg + g * 8, sK[0] + (i * 256 + wave * 64) * 8);
    }
    __syncthreads();

    for (int c = 0; c < 4; ++c) {
        // issue async staging of chunk c+1 into the other buffer
        if (c < 3) {
            const __bf16* Kc = Kg + (size_t)(c + 1) * 128 * 64;
            __bf16* dstb = sK[(c + 1) & 1];
#pragma unroll
            for (int i = 0; i < 4; ++i) {
                const int l = i * 256 + t;
                const int p = l >> 9;
                const int r = (l >> 2) & 127;
                const int j = l & 3;
                const int g = r * 8 + p * 4 + j;
                lds_load16(Kc + g * 8, dstb + (i * 256 + wave * 64) * 8);
            }
        }

        // ---- compute 128x128 tile: sQ x sK[c&1]^T ----
        const __bf16* sKc = sK[c & 1];
        f4 acc[4][4] = {};
#pragma unroll
        for (int kp = 0; kp < 2; ++kp) {
            bf8 af[4], bfr[4];
#pragma unroll
            for (int mi = 0; mi < 4; ++mi)
                af[mi] = *(const bf8*)(sQ + kp * 4096 + (wm + mi * 16 + m16) * 32 + quad * 8);
#pragma unroll
            for (int ni = 0; ni < 4; ++ni)
                bfr[ni] = *(const bf8*)(sKc + kp * 4096 + (wn + ni * 16 + m16) * 32 + quad * 8);
#pragma unroll
            for (int mi = 0; mi < 4; ++mi)
#pragma unroll
                for (int ni = 0; ni < 4; ++ni)
                    acc[mi][ni] = __builtin_amdgcn_mfma_f32_16x16x32_bf16(
                        af[mi], bfr[ni], acc[mi][ni], 0, 0, 0);
        }

        // ---- epilogue for this 128-col chunk ----
        const int colTile = c * 128;
#pragma unroll
        for (int ni = 0; ni < 4; ++ni) {
            const int n = colTile + wn + ni * 16 + m16;
            const float pad    = amask[b * 512 + n];
            const float padoff = (1.0f - pad) * NEG_INF_F;
#pragma unroll
            for (int mi = 0; mi < 4; ++mi) {
#pragma unroll
                for (int r = 0; r < 4; ++r) {
                    const int m = rowTile + wm + mi * 16 + quad * 4 + r;
                    float v = acc[mi][ni][r] * pad - padoff;
                    if (n < m) v -= NEG_INF_F;   // tril(-1) causal-past mask
                    out[((size_t)(be * 512 + m) << 9) + n] = v * 0.125f;
                }
            }
        }
        __syncthreads();   // all waves done with sK[c&1]; chunk c+1 staged
    }
}

// ---------- launch ----------
extern "C" void kernel_launch(void* const* d_in, const int* in_sizes, int n_in,
                              void* d_out, int out_size, void* d_ws, size_t ws_size,
                              hipStream_t stream) {
    const float* lhs   = (const float*)d_in[0];  // 16*512*768
    const float* amask = (const float*)d_in[1];  // 16*512
    const float* W     = (const float*)d_in[2];  // 768*1152
    const float* bias  = (const float*)d_in[3];  // 1152
    float* out = (float*)d_out;

    char* ws = (char*)d_ws;
    __bf16* Abf = (__bf16*)ws;                       // 8192*768*2   = 12,582,912 B
    __bf16* Wt  = (__bf16*)(ws + 12582912);          // 1152*768*2   =  1,769,472 B
    __bf16* qb  = (__bf16*)(ws + 14352384);          // 144*512*64*2 =  9,437,184 B
    __bf16* kb  = (__bf16*)(ws + 23789568);          // 144*512*64*2 =  9,437,184 B

    cast_a_kernel<<<6144, 256, 0, stream>>>(lhs, Abf, 1572864);      // 6291456/4
    transpose_w_kernel<<<dim3(36, 24), 256, 0, stream>>>(W, Wt);
    proj_rope_kernel<<<dim3(9, 64), 256, 0, stream>>>(Abf, Wt, bias, qb, kb);
    logits_kernel<<<dim3(4, 144), 256, 0, stream>>>(qb, kb, amask, out);
}